// Round 5
// baseline (285.233 us; speedup 1.0000x reference)
//
#include <hip/hip_runtime.h>
#include <math.h>

#define NHID 128

typedef __attribute__((ext_vector_type(8))) short bf16x8;
typedef __attribute__((ext_vector_type(4))) float f32x4;

union BF8 { ushort u[8]; bf16x8 v; };

__device__ __forceinline__ ushort f2bf(float f) {
    unsigned int u = __float_as_uint(f);
    u += 0x7FFFu + ((u >> 16) & 1u);      // round-to-nearest-even
    return (ushort)(u >> 16);
}

// Branch-free GELU (A&S 7.1.26 erf, max err ~1.5e-7)
__device__ __forceinline__ float gelu_fast(float x) {
    float ax = fabsf(x);
    float t  = __builtin_amdgcn_rcpf(fmaf(0.23165493f, ax, 1.0f));
    float p  = t * fmaf(t, fmaf(t, fmaf(t, fmaf(t, 1.061405429f, -1.453152027f),
                                        1.421413741f), -0.284496736f), 0.254829592f);
    float e  = __builtin_amdgcn_exp2f(-0.7213475204f * ax * ax);
    float hax = 0.5f * ax;
    return fmaf(-hax, p * e, 0.5f * x + hax);
}

// ---------------------------------------------------------------------------
// Weight prep: bf16, [col][k] layout so MFMA B-frags are per-lane contiguous 16B.
// ---------------------------------------------------------------------------
__global__ void k_build_wc1t(const float* __restrict__ Wm1, ushort* __restrict__ WC1T) {
    int idx = blockIdx.x * blockDim.x + threadIdx.x;   // 256*320
    int c = idx / 320, k = idx % 320;
    float v;
    if (k < 128) {
        v = (c < 128) ? Wm1[k * 128 + c] : Wm1[(128 + k) * 128 + (c - 128)];
    } else if (k < 256) {
        int kk = k - 128;
        v = (c < 128) ? Wm1[(256 + kk) * 128 + c] : -Wm1[(256 + kk) * 128 + (c - 128)];
    } else {
        int kk = k - 256;
        v = (c < 128) ? 0.0f : Wm1[(384 + kk) * 128 + (c - 128)];
    }
    WC1T[idx] = f2bf(v);
}

__global__ void k_build_wuct(const float* __restrict__ Wu1, const float* __restrict__ Wm2,
                             const float* __restrict__ bm2, ushort* __restrict__ WUCT,
                             float* __restrict__ BV) {
    int idx = blockIdx.x * blockDim.x + threadIdx.x;   // 128*256
    int c = idx >> 8, k = idx & 255;
    float v;
    if (k < 128) {
        v = Wu1[k * 128 + c];
    } else {
        int i = k - 128;
        float acc = 0.f;
        for (int j = 0; j < 128; ++j) acc += Wm2[i * 128 + j] * Wu1[(128 + j) * 128 + c];
        v = acc;
    }
    WUCT[idx] = f2bf(v);
    if (idx < 128) {
        float acc = 0.f;
        for (int j = 0; j < 128; ++j) acc += bm2[j] * Wu1[(128 + j) * 128 + idx];
        BV[idx] = acc;
    }
}

__global__ void k_build_wu2t(const float* __restrict__ Wu2, ushort* __restrict__ WU2T) {
    int idx = blockIdx.x * blockDim.x + threadIdx.x;   // 128*128
    int c = idx >> 7, k = idx & 127;
    WU2T[idx] = f2bf(Wu2[k * 128 + c]);
}

// ---------------------------------------------------------------------------
// Counting-sort pipeline
// ---------------------------------------------------------------------------
__global__ void k_zero_i(int* __restrict__ p, int n) {
    int i = blockIdx.x * blockDim.x + threadIdx.x;
    if (i < n) p[i] = 0;
}
__global__ void k_hist(const int* __restrict__ dst, int* __restrict__ deg, int E) {
    int i = blockIdx.x * blockDim.x + threadIdx.x;
    if (i < E) atomicAdd(&deg[dst[i]], 1);
}
__global__ __launch_bounds__(1024) void k_scan(const int* __restrict__ deg,
                                               int* __restrict__ offs,
                                               int* __restrict__ cursor, int N, int E) {
    __shared__ int wsum[17];
    int tid = threadIdx.x;
    int lane = tid & 63, wid = tid >> 6;
    if (tid == 0) wsum[16] = 0;
    __syncthreads();
    for (int base = 0; base < N; base += 1024) {
        int i = base + tid;
        int v = (i < N) ? deg[i] : 0;
        int incl = v;
        #pragma unroll
        for (int d = 1; d < 64; d <<= 1) {
            int t = __shfl_up(incl, d);
            if (lane >= d) incl += t;
        }
        if (lane == 63) wsum[wid] = incl;
        __syncthreads();
        if (tid == 0) {
            int run = wsum[16];
            #pragma unroll
            for (int k = 0; k < 16; ++k) { int t = wsum[k]; wsum[k] = run; run += t; }
            wsum[16] = run;
        }
        __syncthreads();
        int excl = wsum[wid] + incl - v;
        if (i < N) { offs[i] = excl; cursor[i] = excl; }
        __syncthreads();
    }
    if (tid == 0) offs[N] = E;
}
__global__ void k_scatter(const int* __restrict__ src, const int* __restrict__ dst,
                          const float* __restrict__ w, int* __restrict__ cursor,
                          int2* __restrict__ rec, int E) {
    int i = blockIdx.x * blockDim.x + threadIdx.x;
    if (i < E) {
        int d = dst[i];
        int pos = atomicAdd(&cursor[d], 1);
        rec[pos] = make_int2(src[i], __float_as_int(w[i]));
    }
}

// ---------------------------------------------------------------------------
// K1 (MFMA): [P|Q] = [s|x|t] @ Wc1.  K=320, 256 out cols; P,Q bf16.
// Single barrier: full A tile (64x320 bf16) staged to LDS once; B fragments
// loaded straight from L2 (WC1T is [col][k] -> per-lane contiguous dwordx4).
// Asub stride 328 shorts: 656B = 164 words === 4 (mod 32); frag reads touch
// all 32 banks uniformly; 16B aligned rows.
// ---------------------------------------------------------------------------
__global__ __launch_bounds__(256) void k1_mfma(
    const float* __restrict__ s, const float* __restrict__ x, const float* __restrict__ t,
    const ushort* __restrict__ WC1T, const float* __restrict__ bm1,
    ushort* __restrict__ Pb, ushort* __restrict__ Qb, int N)
{
    __shared__ __align__(16) short Asub[64 * 328];
    int tid = threadIdx.x;
    int w = tid >> 6, l = tid & 63;
    int lr = l & 15;
    int lk = (l >> 4) * 8;
    int n0 = blockIdx.x * 64;

    // ---- stage full A tile, one barrier
    int ar = tid >> 2;              // row 0..63
    int ac = (tid & 3) * 8;         // k-chunk
    int arg = n0 + ar; if (arg > N - 1) arg = N - 1;
    #pragma unroll
    for (int k0 = 0; k0 < 320; k0 += 32) {
        int k = k0 + ac;
        const float* asrc;
        if (k < 128)      asrc = s + (size_t)arg * 128 + k;
        else if (k < 256) asrc = x + (size_t)arg * 128 + (k - 128);
        else              asrc = t + (size_t)arg * 64 + (k - 256);
        float4 f0 = *(const float4*)asrc;
        float4 f1 = *(const float4*)(asrc + 4);
        BF8 pk;
        pk.u[0] = f2bf(f0.x); pk.u[1] = f2bf(f0.y); pk.u[2] = f2bf(f0.z); pk.u[3] = f2bf(f0.w);
        pk.u[4] = f2bf(f1.x); pk.u[5] = f2bf(f1.y); pk.u[6] = f2bf(f1.z); pk.u[7] = f2bf(f1.w);
        *(bf16x8*)&Asub[ar * 328 + k] = pk.v;
    }
    __syncthreads();

    f32x4 acc[4][4];
    #pragma unroll
    for (int i = 0; i < 4; ++i)
        #pragma unroll
        for (int j = 0; j < 4; ++j) acc[i][j] = (f32x4){0.f, 0.f, 0.f, 0.f};

    // B fragment base pointers (per-lane, contiguous 16B each k-step)
    const ushort* bbase[4];
    #pragma unroll
    for (int ct = 0; ct < 4; ++ct)
        bbase[ct] = WC1T + (size_t)(w * 64 + ct * 16 + lr) * 320 + lk;

    #pragma unroll
    for (int k0 = 0; k0 < 320; k0 += 32) {
        bf16x8 bfr[4], afr[4];
        #pragma unroll
        for (int ct = 0; ct < 4; ++ct) bfr[ct] = *(const bf16x8*)(bbase[ct] + k0);
        #pragma unroll
        for (int rt = 0; rt < 4; ++rt) afr[rt] = *(const bf16x8*)&Asub[(rt * 16 + lr) * 328 + k0 + lk];
        #pragma unroll
        for (int rt = 0; rt < 4; ++rt)
            #pragma unroll
            for (int ct = 0; ct < 4; ++ct)
                acc[rt][ct] = __builtin_amdgcn_mfma_f32_16x16x32_bf16(afr[rt], bfr[ct], acc[rt][ct], 0, 0, 0);
    }

    #pragma unroll
    for (int ct = 0; ct < 4; ++ct) {
        int col = w * 64 + ct * 16 + lr;
        float bb = (col >= 128) ? bm1[col - 128] : 0.f;
        #pragma unroll
        for (int rt = 0; rt < 4; ++rt) {
            int rbase = n0 + rt * 16 + (l >> 4) * 4;
            #pragma unroll
            for (int r = 0; r < 4; ++r) {
                int row = rbase + r;
                if (row < N) {
                    float v = acc[rt][ct][r];
                    if (col < 128) Pb[(size_t)row * 128 + col] = f2bf(v);
                    else           Qb[(size_t)row * 128 + (col - 128)] = f2bf(v + bb);
                }
            }
        }
    }
}

// ---------------------------------------------------------------------------
// K_agg: segmented reduction over dst-sorted edges. One wave per dst node,
// 2 channels per lane; readlane broadcast; bf16 P,Q; branch-free gelu.
// ---------------------------------------------------------------------------
__global__ __launch_bounds__(256) void k_agg(
    const ushort* __restrict__ Pb, const ushort* __restrict__ Qb,
    const int2* __restrict__ rec, const int* __restrict__ offs,
    ushort* __restrict__ GAB, float* __restrict__ sw, int N)
{
    int n = blockIdx.x * 4 + (threadIdx.x >> 6);
    if (n >= N) return;
    int lane = threadIdx.x & 63;
    int beg = offs[n], end = offs[n + 1];
    unsigned int qv = *(const unsigned int*)&Qb[(size_t)n * 128 + lane * 2];
    float qx = __uint_as_float(qv << 16);
    float qy = __uint_as_float(qv & 0xffff0000u);
    float a0 = 0.f, a1 = 0.f, wsum = 0.f;
    for (int base = beg; base < end; base += 64) {
        int cnt = end - base; if (cnt > 64) cnt = 64;
        int2 r = make_int2(0, 0);
        if (lane < cnt) r = rec[base + lane];
        int j = 0;
        for (; j + 1 < cnt; j += 2) {
            int   s0 = __builtin_amdgcn_readlane(r.x, j);
            float w0 = __int_as_float(__builtin_amdgcn_readlane(r.y, j));
            int   s1 = __builtin_amdgcn_readlane(r.x, j + 1);
            float w1 = __int_as_float(__builtin_amdgcn_readlane(r.y, j + 1));
            unsigned int p0 = *(const unsigned int*)&Pb[(size_t)s0 * 128 + lane * 2];
            unsigned int p1 = *(const unsigned int*)&Pb[(size_t)s1 * 128 + lane * 2];
            float p0x = __uint_as_float(p0 << 16);
            float p0y = __uint_as_float(p0 & 0xffff0000u);
            float p1x = __uint_as_float(p1 << 16);
            float p1y = __uint_as_float(p1 & 0xffff0000u);
            a0 = fmaf(w0, gelu_fast(p0x + qx), a0);
            a1 = fmaf(w0, gelu_fast(p0y + qy), a1);
            a0 = fmaf(w1, gelu_fast(p1x + qx), a0);
            a1 = fmaf(w1, gelu_fast(p1y + qy), a1);
            wsum += w0 + w1;
        }
        if (j < cnt) {
            int   s0 = __builtin_amdgcn_readlane(r.x, j);
            float w0 = __int_as_float(__builtin_amdgcn_readlane(r.y, j));
            unsigned int p0 = *(const unsigned int*)&Pb[(size_t)s0 * 128 + lane * 2];
            float p0x = __uint_as_float(p0 << 16);
            float p0y = __uint_as_float(p0 & 0xffff0000u);
            a0 = fmaf(w0, gelu_fast(p0x + qx), a0);
            a1 = fmaf(w0, gelu_fast(p0y + qy), a1);
            wsum += w0;
        }
    }
    ushort2 g2 = make_ushort2(f2bf(a0), f2bf(a1));
    *(ushort2*)&GAB[(size_t)n * 128 + lane * 2] = g2;
    if (lane == 0) sw[n] = wsum;
}

// ---------------------------------------------------------------------------
// K3 (MFMA): fused update MLP, 2 barriers total.
// Phase A: pre2 = [s|agg] @ Wuc (K=256); A tile staged once (stride 264);
// B frags direct from L2.  Epilogue -> H2 (bf16 LDS).  Phase B: out = h2@Wu2.
// ---------------------------------------------------------------------------
__global__ __launch_bounds__(256) void k3_mfma(
    const float* __restrict__ s, const ushort* __restrict__ GAB, const float* __restrict__ sw,
    const ushort* __restrict__ WUCT, const float* __restrict__ BV, const float* __restrict__ bu1,
    const ushort* __restrict__ WU2T, const float* __restrict__ bu2,
    float* __restrict__ out, int N)
{
    __shared__ __align__(16) short Asub[64 * 264];   // 528B rows: ===4 banks mod 32, 16B aligned
    __shared__ __align__(16) short H2[64 * 136];     // 272B rows
    __shared__ float SWs[64];
    int tid = threadIdx.x;
    int w = tid >> 6, l = tid & 63;
    int lr = l & 15, lk = (l >> 4) * 8;
    int n0 = blockIdx.x * 64;

    if (tid < 64) SWs[tid] = (n0 + tid < N) ? sw[n0 + tid] : 0.f;

    // ---- stage full A tile ([s|agg] -> bf16), one barrier
    int ar = tid >> 2;
    int ac = (tid & 3) * 8;
    int arg = n0 + ar; if (arg > N - 1) arg = N - 1;
    #pragma unroll
    for (int k0 = 0; k0 < 256; k0 += 32) {
        int k = k0 + ac;
        BF8 pk;
        if (k < 128) {
            const float* asrc = s + (size_t)arg * 128 + k;
            float4 f0 = *(const float4*)asrc;
            float4 f1 = *(const float4*)(asrc + 4);
            pk.u[0] = f2bf(f0.x); pk.u[1] = f2bf(f0.y); pk.u[2] = f2bf(f0.z); pk.u[3] = f2bf(f0.w);
            pk.u[4] = f2bf(f1.x); pk.u[5] = f2bf(f1.y); pk.u[6] = f2bf(f1.z); pk.u[7] = f2bf(f1.w);
        } else {
            pk.v = *(const bf16x8*)(GAB + (size_t)arg * 128 + (k - 128));
        }
        *(bf16x8*)&Asub[ar * 264 + k] = pk.v;
    }
    __syncthreads();

    // ---- Phase A: K=256, cols 128 (wave w: cols w*32..+31)
    f32x4 acc[4][2];
    #pragma unroll
    for (int i = 0; i < 4; ++i) { acc[i][0] = (f32x4){0,0,0,0}; acc[i][1] = (f32x4){0,0,0,0}; }

    const ushort* b1base[2];
    #pragma unroll
    for (int ct = 0; ct < 2; ++ct)
        b1base[ct] = WUCT + (size_t)(w * 32 + ct * 16 + lr) * 256 + lk;

    #pragma unroll
    for (int k0 = 0; k0 < 256; k0 += 32) {
        bf16x8 bfr[2], afr[4];
        #pragma unroll
        for (int ct = 0; ct < 2; ++ct) bfr[ct] = *(const bf16x8*)(b1base[ct] + k0);
        #pragma unroll
        for (int rt = 0; rt < 4; ++rt) afr[rt] = *(const bf16x8*)&Asub[(rt * 16 + lr) * 264 + k0 + lk];
        #pragma unroll
        for (int rt = 0; rt < 4; ++rt)
            #pragma unroll
            for (int ct = 0; ct < 2; ++ct)
                acc[rt][ct] = __builtin_amdgcn_mfma_f32_16x16x32_bf16(afr[rt], bfr[ct], acc[rt][ct], 0, 0, 0);
    }

    // epilogue A: bias + sw*BV, gelu, -> H2 bf16
    #pragma unroll
    for (int ct = 0; ct < 2; ++ct) {
        int col = w * 32 + ct * 16 + lr;
        float b1 = bu1[col], bv = BV[col];
        #pragma unroll
        for (int rt = 0; rt < 4; ++rt) {
            int rbase = rt * 16 + (l >> 4) * 4;
            #pragma unroll
            for (int r = 0; r < 4; ++r) {
                int row = rbase + r;
                float v = acc[rt][ct][r] + b1 + SWs[row] * bv;
                H2[row * 136 + col] = (short)f2bf(gelu_fast(v));
            }
        }
    }
    __syncthreads();

    // ---- Phase B: out = h2 @ Wu2 (K=128)
    f32x4 acc2[4][2];
    #pragma unroll
    for (int i = 0; i < 4; ++i) { acc2[i][0] = (f32x4){0,0,0,0}; acc2[i][1] = (f32x4){0,0,0,0}; }

    const ushort* b2base[2];
    #pragma unroll
    for (int ct = 0; ct < 2; ++ct)
        b2base[ct] = WU2T + (size_t)(w * 32 + ct * 16 + lr) * 128 + lk;

    #pragma unroll
    for (int k0 = 0; k0 < 128; k0 += 32) {
        bf16x8 bfr[2], afr[4];
        #pragma unroll
        for (int ct = 0; ct < 2; ++ct) bfr[ct] = *(const bf16x8*)(b2base[ct] + k0);
        #pragma unroll
        for (int rt = 0; rt < 4; ++rt) afr[rt] = *(const bf16x8*)&H2[(rt * 16 + lr) * 136 + k0 + lk];
        #pragma unroll
        for (int rt = 0; rt < 4; ++rt)
            #pragma unroll
            for (int ct = 0; ct < 2; ++ct)
                acc2[rt][ct] = __builtin_amdgcn_mfma_f32_16x16x32_bf16(afr[rt], bfr[ct], acc2[rt][ct], 0, 0, 0);
    }

    #pragma unroll
    for (int ct = 0; ct < 2; ++ct) {
        int col = w * 32 + ct * 16 + lr;
        float b2 = bu2[col];
        #pragma unroll
        for (int rt = 0; rt < 4; ++rt) {
            int rbase = n0 + rt * 16 + (l >> 4) * 4;
            #pragma unroll
            for (int r = 0; r < 4; ++r) {
                int row = rbase + r;
                if (row < N) out[(size_t)row * 128 + col] = acc2[rt][ct][r] + b2;
            }
        }
    }
}

// ---------------------------------------------------------------------------
extern "C" void kernel_launch(void* const* d_in, const int* in_sizes, int n_in,
                              void* d_out, int out_size, void* d_ws, size_t ws_size,
                              hipStream_t stream) {
    const float* s    = (const float*)d_in[0];
    const float* x    = (const float*)d_in[1];
    const int*   ei   = (const int*)d_in[2];
    const float* ew   = (const float*)d_in[3];
    const float* t    = (const float*)d_in[4];
    const float* Wm1  = (const float*)d_in[5];
    const float* bm1  = (const float*)d_in[6];
    const float* Wm2  = (const float*)d_in[7];
    const float* bm2  = (const float*)d_in[8];
    const float* Wu1  = (const float*)d_in[9];
    const float* bu1  = (const float*)d_in[10];
    const float* Wu2  = (const float*)d_in[11];
    const float* bu2  = (const float*)d_in[12];

    int N = in_sizes[0] / 128;
    int E = in_sizes[2] / 2;
    const int* srcI = ei;
    const int* dstI = ei + E;

    // workspace layout (32-bit words)
    float* ws = (float*)d_ws;
    size_t off = 0;
    ushort* Pb   = (ushort*)(ws + off); off += (size_t)N * 64;          // N*128 bf16
    ushort* Qb   = (ushort*)(ws + off); off += (size_t)N * 64;          // N*128 bf16
    float*  SW   = ws + off; off += ((size_t)N + 63) & ~(size_t)63;
    ushort* GAB  = (ushort*)(ws + off); off += (size_t)N * 64;          // N*128 bf16
    ushort* WC1T = (ushort*)(ws + off); off += (256 * 320) / 2;
    ushort* WUCT = (ushort*)(ws + off); off += (128 * 256) / 2;
    ushort* WU2T = (ushort*)(ws + off); off += (128 * 128) / 2;
    float*  BV   = ws + off; off += 128;
    int*    DEG  = (int*)(ws + off); off += (size_t)N;
    int*    OFFS = (int*)(ws + off); off += (size_t)N + 64;
    int*    CUR  = (int*)(ws + off); off += (size_t)N;
    off = (off + 1) & ~(size_t)1;
    int2*   REC  = (int2*)(ws + off); off += (size_t)E * 2;

    // weight prep
    k_build_wc1t<<<(256 * 320) / 256, 256, 0, stream>>>(Wm1, WC1T);
    k_build_wuct<<<(128 * 256) / 256, 256, 0, stream>>>(Wu1, Wm2, bm2, WUCT, BV);
    k_build_wu2t<<<(128 * 128) / 256, 256, 0, stream>>>(Wu2, WU2T);

    // counting sort by dst
    k_zero_i<<<(N + 255) / 256, 256, 0, stream>>>(DEG, N);
    k_hist<<<(E + 255) / 256, 256, 0, stream>>>(dstI, DEG, E);
    k_scan<<<1, 1024, 0, stream>>>(DEG, OFFS, CUR, N, E);
    k_scatter<<<(E + 255) / 256, 256, 0, stream>>>(srcI, dstI, ew, CUR, REC, E);

    // node precompute (MFMA, single-barrier)
    int nb = (N + 63) / 64;
    k1_mfma<<<nb, 256, 0, stream>>>(s, x, t, WC1T, bm1, Pb, Qb, N);

    // segmented aggregation
    k_agg<<<(N + 3) / 4, 256, 0, stream>>>(Pb, Qb, REC, OFFS, GAB, SW, N);

    // update MLP (MFMA, fused, 2 barriers)
    k3_mfma<<<nb, 256, 0, stream>>>(s, GAB, SW, WUCT, BV, bu1, WU2T, bu2, (float*)d_out, N);
}